// Round 2
// baseline (451.762 us; speedup 1.0000x reference)
//
#include <hip/hip_runtime.h>
#include <math.h>

#define HS 4096
#define NIN 17
#define ROW_CHUNKS 512
#define ROWS_PER_CHUNK 8                 // HS / ROW_CHUNKS
#define NSQ ((size_t)HS * (size_t)HS)
// The concatenated output buffer puts hebb/et/pw at float offset == 1 (mod 4).
// We store through (out_X + 3), which IS 16B-aligned, as NG4 shifted float4
// groups: group j' covers floats [3+4j', 6+4j'] of the array. Head floats
// 0,1,2 and tail float NSQ-1 are patched by a dedicated block.
#define NG4 4194303u                     // (NSQ - 4) / 4

typedef float vfloat4 __attribute__((ext_vector_type(4)));

__device__ __forceinline__ vfloat4 ntload4(const vfloat4* p) {
  return __builtin_nontemporal_load(p);
}
__device__ __forceinline__ void ntstore4(vfloat4* p, vfloat4 v) {
  __builtin_nontemporal_store(v, p);
}
// Shifted group j' of dst = {srcA.w, srcB.xyz} where srcA=group j', srcB=j'+1.
__device__ __forceinline__ vfloat4 shift3(vfloat4 a, vfloat4 b) {
  return __builtin_shufflevector(a, b, 3, 4, 5, 6);
}

// Kernel 1: matvec partials of hidden @ (w + alpha*hebb), fused with the et
// pass-through (aligned dwordx4 both sides via the shift trick). grid (4,512).
// w/alpha/et are single-use -> nt loads; hebb is re-read by kernel 3 -> normal
// (allocating) load so it stays L2/L3-resident.
__global__ __launch_bounds__(256) void matvec_et_k(
    const float* __restrict__ hidden, const float* __restrict__ w,
    const float* __restrict__ alpha, const float* __restrict__ hebb,
    const float* __restrict__ et, float* __restrict__ out_et3,  // out_et+3, 16B-aligned
    float* __restrict__ partial) {
  const int tid = threadIdx.x;
  const int j4 = blockIdx.x * 256 + tid;                 // float4 col, 0..1023
  const int row0 = blockIdx.y * ROWS_PER_CHUNK;
  const size_t base = (size_t)row0 * (HS / 4) + j4;
  const vfloat4* wp = reinterpret_cast<const vfloat4*>(w) + base;
  const vfloat4* ap = reinterpret_cast<const vfloat4*>(alpha) + base;
  const vfloat4* bp = reinterpret_cast<const vfloat4*>(hebb) + base;
  const vfloat4* ep = reinterpret_cast<const vfloat4*>(et);
  vfloat4* oe = reinterpret_cast<vfloat4*>(out_et3);

  // Matvec loads first: 24 independent 16B loads in flight (~MLP >> latency-BW).
  vfloat4 wv[ROWS_PER_CHUNK], av[ROWS_PER_CHUNK], bv[ROWS_PER_CHUNK];
#pragma unroll
  for (int r = 0; r < ROWS_PER_CHUNK; ++r) {
    wv[r] = ntload4(wp + (size_t)r * (HS / 4));
    av[r] = ntload4(ap + (size_t)r * (HS / 4));
    bv[r] = bp[(size_t)r * (HS / 4)];
  }

  // et copy: 8 batches, lane-contiguous shifted groups (coalesced stores).
  const unsigned s0 = (blockIdx.y * 4u + blockIdx.x) * 2048u + tid;
#pragma unroll
  for (int m = 0; m < 8; ++m) {
    const unsigned s = s0 + 256u * m;
    const unsigned sc = (s < NG4) ? s : (NG4 - 1u);      // clamp the single OOB slot
    const vfloat4 a = ntload4(ep + sc);
    const vfloat4 b = ntload4(ep + sc + 1);
    if (s < NG4) ntstore4(oe + s, shift3(a, b));
  }

  vfloat4 acc = (vfloat4)(0.f);
#pragma unroll
  for (int r = 0; r < ROWS_PER_CHUNK; ++r) {
    const float h = hidden[row0 + r];                    // block-uniform -> s_load
#pragma unroll
    for (int c = 0; c < 4; ++c)
      acc[c] = fmaf(h, fmaf(av[r][c], bv[r][c], wv[r][c]), acc[c]);
  }
  reinterpret_cast<vfloat4*>(partial)[(size_t)blockIdx.y * (HS / 4) + j4] = acc;
}

// Kernel 2: coalesced reduction of 512 partials + i2h + bias + tanh.
__global__ __launch_bounds__(256) void finalize_k(
    const float* __restrict__ partial, const float* __restrict__ inputs,
    const float* __restrict__ i2h_w, const float* __restrict__ i2h_b,
    float* __restrict__ out_hactiv) {
  const int t = threadIdx.x;
  const int col = blockIdx.x * 64 + (t & 63);
  const int g = t >> 6;                                  // 4 chunk groups
  float acc = 0.f;
#pragma unroll 16
  for (int k = 0; k < ROW_CHUNKS / 4; ++k)
    acc += partial[(size_t)(g * (ROW_CHUNKS / 4) + k) * HS + col];

  __shared__ float red[256];
  red[t] = acc;
  __syncthreads();
  if (t < 64) {
    float s = red[t] + red[t + 64] + red[t + 128] + red[t + 192];
#pragma unroll
    for (int l = 0; l < NIN; ++l)
      s = fmaf(inputs[l], i2h_w[(size_t)col * NIN + l], s);
    out_hactiv[col] = tanhf(s + i2h_b[col]);
  }
}

// Kernel 3: hebb update + pw pass-through (aligned dwordx4 streams), with the
// 5 output heads and the 4 head/tail scalars-per-array folded into spare
// blocks. Blocks 0..2047: streaming; 2048..2052: heads; 2053: scalar patch.
__global__ __launch_bounds__(256) void hebb_pw_heads_k(
    const float* __restrict__ hebb, const float* __restrict__ hidden,
    const float* __restrict__ hactiv, const float* __restrict__ eta,
    const float* __restrict__ pw, const float* __restrict__ et,
    float* __restrict__ out_hebb, float* __restrict__ out_et,
    float* __restrict__ out_pw,
    const float* __restrict__ h2o_w, const float* __restrict__ h2o_b,
    const float* __restrict__ h2v_w, const float* __restrict__ h2v_b,
    float* __restrict__ out_heads) {
  const int b = blockIdx.x;
  if (b >= 2048) {
    if (b < 2053) {                                      // heads: row b-2048
      const int r = b - 2048;
      const float* wrow = (r < 4) ? (h2o_w + (size_t)r * HS) : h2v_w;
      float s = 0.f;
      for (int j = threadIdx.x; j < HS; j += 256) s = fmaf(hactiv[j], wrow[j], s);
      __shared__ float red[256];
      red[threadIdx.x] = s;
      __syncthreads();
      for (int off = 128; off > 0; off >>= 1) {
        if (threadIdx.x < off) red[threadIdx.x] += red[threadIdx.x + off];
        __syncthreads();
      }
      if (threadIdx.x == 0) out_heads[r] = red[0] + ((r < 4) ? h2o_b[r] : h2v_b[0]);
    } else if (threadIdx.x == 0) {                       // head/tail scalar patch
      const float e = eta[0], om = 1.f - e;
      const float f0 = e * hidden[0], fl = e * hidden[HS - 1];
#pragma unroll
      for (int k = 0; k < 3; ++k) {
        out_et[k] = et[k];
        out_pw[k] = pw[k];
        out_hebb[k] = fmaf(om, hebb[k], f0 * hactiv[k]);
      }
      out_et[NSQ - 1] = et[NSQ - 1];
      out_pw[NSQ - 1] = pw[NSQ - 1];
      out_hebb[NSQ - 1] = fmaf(om, hebb[NSQ - 1], fl * hactiv[HS - 1]);
    }
    return;
  }

  const float e = eta[0], om = 1.f - e;
  const vfloat4* hebbp = reinterpret_cast<const vfloat4*>(hebb);
  const vfloat4* pwp = reinterpret_cast<const vfloat4*>(pw);
  vfloat4* oheb = reinterpret_cast<vfloat4*>(out_hebb + 3);   // 16B-aligned
  vfloat4* opw = reinterpret_cast<vfloat4*>(out_pw + 3);      // 16B-aligned
  const unsigned s0 = b * 2048u + threadIdx.x;
#pragma unroll
  for (int m = 0; m < 8; ++m) {
    const unsigned s = s0 + 256u * m;
    const unsigned sc = (s < NG4) ? s : (NG4 - 1u);
    // pw copy (pure stream, nt both sides)
    const vfloat4 pA = ntload4(pwp + sc);
    const vfloat4 pB = ntload4(pwp + sc + 1);
    // hebb update computed on ALIGNED groups (row/col clean: groups never
    // cross rows since 1024 groups/row), then shifted for the aligned store.
    const vfloat4 hA = hebbp[sc];                        // L2/L3-warm from k1
    const vfloat4 hB = hebbp[sc + 1];
    const unsigned rA = sc >> 10, rB = (sc + 1) >> 10;
    const unsigned cA = (sc & 1023u) * 4u, cB = ((sc + 1) & 1023u) * 4u;
    const float fA = e * hidden[rA], fB = e * hidden[rB];
    vfloat4 oA, oB;
#pragma unroll
    for (int c = 0; c < 4; ++c) {
      oA[c] = fmaf(om, hA[c], fA * hactiv[cA + c]);
      oB[c] = fmaf(om, hB[c], fB * hactiv[cB + c]);
    }
    if (s < NG4) {
      ntstore4(opw + s, shift3(pA, pB));
      ntstore4(oheb + s, shift3(oA, oB));
    }
  }
}

extern "C" void kernel_launch(void* const* d_in, const int* in_sizes, int n_in,
                              void* d_out, int out_size, void* d_ws, size_t ws_size,
                              hipStream_t stream) {
  const float* inputs = (const float*)d_in[0];
  const float* hidden = (const float*)d_in[1];
  const float* hebb   = (const float*)d_in[2];
  const float* et     = (const float*)d_in[3];
  const float* pw     = (const float*)d_in[4];
  const float* i2h_w  = (const float*)d_in[5];
  const float* i2h_b  = (const float*)d_in[6];
  const float* w      = (const float*)d_in[7];
  const float* alpha  = (const float*)d_in[8];
  const float* eta    = (const float*)d_in[9];
  const float* h2o_w  = (const float*)d_in[10];
  const float* h2o_b  = (const float*)d_in[11];
  const float* h2v_w  = (const float*)d_in[12];
  const float* h2v_b  = (const float*)d_in[13];

  float* out = (float*)d_out;
  float* out_heads  = out;               // activout[4] + valueout[1]
  float* out_hactiv = out + 5;           // [HS]      (float offset 5)
  float* out_hebb   = out + 5 + HS;      // [HS*HS]   (float offset 4101 == 1 mod 4)
  float* out_et     = out_hebb + NSQ;    //           (== 1 mod 4)
  float* out_pw     = out_et + NSQ;      //           (== 1 mod 4)

  // Partial scratch: 512*4096 floats = 8 MB. Prefer d_ws; else an aligned
  // slice of the hebb output region (consumed by finalize_k before
  // hebb_pw_heads_k overwrites it — stream-ordered, safe).
  const size_t need = (size_t)ROW_CHUNKS * HS * sizeof(float);
  float* partial = (ws_size >= need) ? (float*)d_ws
                                     : (out_hebb + 3 /* float off 4104, 16B-aligned */);

  hipLaunchKernelGGL(matvec_et_k, dim3(4, ROW_CHUNKS), dim3(256), 0, stream,
                     hidden, w, alpha, hebb, et, out_et + 3, partial);
  hipLaunchKernelGGL(finalize_k, dim3(HS / 64), dim3(256), 0, stream,
                     partial, inputs, i2h_w, i2h_b, out_hactiv);
  hipLaunchKernelGGL(hebb_pw_heads_k, dim3(2054), dim3(256), 0, stream,
                     hebb, hidden, out_hactiv, eta, pw, et,
                     out_hebb, out_et, out_pw,
                     h2o_w, h2o_b, h2v_w, h2v_b, out_heads);
}